// Round 7
// baseline (262.358 us; speedup 1.0000x reference)
//
#include <hip/hip_runtime.h>
#include <hip/hip_bf16.h>

// C[32768,2304] = A[32768,768] * W^T + b ; outputs q,k,v [32768,768] fp32 each.
#define M_TOT 32768
#define K_TOT 768
#define N_TOT 2304
#define H     768
#define BM 128
#define BN 128
#define NBN 18                   // N_TOT/BN
#define NBM 256                  // M_TOT/BM
#define NBLK (NBM*NBN)           // 4608, %8==0 -> XCD swizzle bijective
#define NST  24                  // sub-tiles of BK=32
#define OUT_PER 25165824         // M_TOT*H

typedef __attribute__((ext_vector_type(8))) short bf16x8;
typedef __attribute__((ext_vector_type(8))) unsigned short u16x8;
typedef __attribute__((ext_vector_type(4))) float f32x4;

__device__ __forceinline__ void gld_lds16(const void* g, void* l) {
    __builtin_amdgcn_global_load_lds(
        (const __attribute__((address_space(1))) unsigned int*)g,
        (__attribute__((address_space(3))) unsigned int*)l,
        16, 0, 0);
}

__device__ __forceinline__ unsigned short f2bf_rne(float f) {
    unsigned u = __builtin_bit_cast(unsigned, f);
    unsigned r = (u + 0x7FFFu + ((u >> 16) & 1u)) >> 16;
    return (unsigned short)r;
}

// ---------------------------------------------------------------------------
// Pass 1 (R3-proven, ~25us): fp32 -> bf16 convert + pack into tiled layout
// pk[gran][kt][kb8][row128][8]; granule = 128 rows x 768 k = 98304 elems.
// Sub-tile (BK=32) u = 2*kt+kk is contiguous 4096 elems at u*4096.
// ---------------------------------------------------------------------------
#define A_TILES 3072             // 256 m-granules x 12 k-tiles
#define W_TILES 216              // 18 row-granules x 12 k-tiles
#define LDSW 68

__global__ void convert_pack(const float* __restrict__ A,
                             const float* __restrict__ wq, const float* __restrict__ wk,
                             const float* __restrict__ wv,
                             const float* __restrict__ bq, const float* __restrict__ bk,
                             const float* __restrict__ bv,
                             unsigned short* __restrict__ A_pk,
                             unsigned short* __restrict__ W_pk,
                             float* __restrict__ biasb) {
    __shared__ float lds_f[128 * LDSW];

    const int tid = threadIdx.x;
    const int t   = blockIdx.x;

    int gt = t * 256 + tid;
    if (gt < 2304) {
        biasb[gt] = (gt < 768) ? bq[gt] : (gt < 1536) ? bk[gt - 768] : bv[gt - 1536];
    }

    const float* src;
    unsigned short* dst;
    if (t < A_TILES) {
        const int mt = t / 12, kt = t - mt * 12;
        src = A + (size_t)mt * 128 * K_TOT + kt * 64;
        dst = A_pk + (size_t)t * 8192;
    } else {
        const int t2 = t - A_TILES;
        const int nt = t2 / 12, kt = t2 - nt * 12;
        const int which = nt / 6;
        const int row0  = (nt - which * 6) * 128;
        const float* w = (which == 0) ? wq : (which == 1) ? wk : wv;
        src = w + (size_t)row0 * K_TOT + kt * 64;
        dst = W_pk + (size_t)t2 * 8192;
    }

    #pragma unroll
    for (int j = 0; j < 8; ++j) {
        int f = j * 256 + tid;
        int row = f >> 4, c4 = f & 15;
        float4 v = *reinterpret_cast<const float4*>(src + (size_t)row * K_TOT + c4 * 4);
        *reinterpret_cast<float4*>(&lds_f[row * LDSW + c4 * 4]) = v;
    }
    __syncthreads();

    #pragma unroll
    for (int j = 0; j < 4; ++j) {
        int c = j * 256 + tid;
        int kb = c >> 7, row = c & 127;
        const float* p = &lds_f[row * LDSW + kb * 8];
        u16x8 o;
        #pragma unroll
        for (int e = 0; e < 8; ++e) o[e] = f2bf_rne(p[e]);
        *reinterpret_cast<u16x8*>(dst + (size_t)c * 8) = o;
    }
}

// ---------------------------------------------------------------------------
// Pass 2: OCCUPANCY-FIRST 128x128 bf16 MFMA GEMM (R3 structure, BK=32):
//   256 thr = 4 waves (2x2), wave tile 64x64, acc[4][4].
//   LDS = 16 KiB single-buffered -> __launch_bounds__(256,5): 5 blocks/CU
//   (20 waves/CU = 5 waves/SIMD) so independent blocks cover each other's
//   barrier drains (m114 wave-level overlap). Fully compiler-scheduled:
//   no asm waitcnt, no sched_barrier, no setprio (the regime that wins).
//   Packed slot [q4][row128][8]: ds_read_b128 conflict-free (measured 0).
//   24 sub-tiles of BK=32; per sub-tile: stage 4 gld_lds / 8 ds_read_b128
//   / 16 MFMA per wave.
// ---------------------------------------------------------------------------
__global__ __launch_bounds__(256, 5) void qkv_gemm(
        const unsigned short* __restrict__ A_pk,
        const unsigned short* __restrict__ W_pk,
        const float* __restrict__ bias,
        float* __restrict__ out) {

    __shared__ __align__(16) unsigned short sA[4096];   // 8 KiB: 128 rows x 32 k
    __shared__ __align__(16) unsigned short sB[4096];   // 8 KiB

    const int tid  = threadIdx.x;
    const int lane = tid & 63;
    const int wid  = tid >> 6;     // 0..3
    const int wr   = wid >> 1;     // 0..1 : rows wr*64..+63
    const int wc   = wid & 1;      // 0..1 : cols wc*64..+63

    int bid = (int)blockIdx.x;
    bid = (bid & 7) * (NBLK / 8) + (bid >> 3);   // XCD-aware (bijective)
    const int bm = bid / NBN;
    const int bn = bid - bm * NBN;
    const int m0 = bm * BM;
    const int n0 = bn * BN;

    // granule bases (granule = 128 rows x 768 k = 98304 elems; 24 sub-tiles
    // of 4096 elems each, sub-tile u contiguous at u*4096)
    const unsigned short* aG = A_pk + (size_t)bm * 98304;
    const unsigned short* bG = W_pk + (size_t)bn * 98304;

    f32x4 acc[4][4];
    #pragma unroll
    for (int i = 0; i < 4; ++i)
        #pragma unroll
        for (int j = 0; j < 4; ++j)
            acc[i][j] = (f32x4){0.f, 0.f, 0.f, 0.f};

    // fragment read byte-offsets within slot [q4][row128][8]:
    //   af[mi] at aOff + mi*256 ; bf[nj] at bOff + nj*256
    const int aOff = ((lane >> 4) << 11) + (wr * 64 + (lane & 15)) * 16;
    const int bOff = ((lane >> 4) << 11) + (wc * 64 + (lane & 15)) * 16;

    for (int u = 0; u < NST; ++u) {
        if (u) __syncthreads();
        {
            const unsigned short* aS = aG + (size_t)u * 4096;
            const unsigned short* bS = bG + (size_t)u * 4096;
            gld_lds16(aS + tid * 8,          &sA[tid * 8]);
            gld_lds16(aS + 2048 + tid * 8,   &sA[2048 + tid * 8]);
            gld_lds16(bS + tid * 8,          &sB[tid * 8]);
            gld_lds16(bS + 2048 + tid * 8,   &sB[2048 + tid * 8]);
        }
        __syncthreads();

        bf16x8 af[4], bf[4];
        #pragma unroll
        for (int i = 0; i < 4; ++i)
            af[i] = *reinterpret_cast<const bf16x8*>((const char*)sA + aOff + i * 256);
        #pragma unroll
        for (int j = 0; j < 4; ++j)
            bf[j] = *reinterpret_cast<const bf16x8*>((const char*)sB + bOff + j * 256);
        #pragma unroll
        for (int i = 0; i < 4; ++i)
            #pragma unroll
            for (int j = 0; j < 4; ++j)
                // swapped operands: lane's 4 acc regs = 4 consecutive n
                acc[i][j] = __builtin_amdgcn_mfma_f32_16x16x32_bf16(
                    bf[j], af[i], acc[i][j], 0, 0, 0);
    }

    // ---- epilogue: operand-swapped layout -> float4 stores
    const int which = n0 / H;
    const int c0    = n0 - which * H;
    float* outB = out + (size_t)which * OUT_PER;

    #pragma unroll
    for (int j = 0; j < 4; ++j) {
        const int ncol = wc * 64 + j * 16 + ((lane >> 4) << 2);
        const float4 bv4 = *reinterpret_cast<const float4*>(&bias[n0 + ncol]);
        #pragma unroll
        for (int i = 0; i < 4; ++i) {
            const int mrow = m0 + wr * 64 + i * 16 + (lane & 15);
            float4 o;
            o.x = acc[i][j][0] + bv4.x;
            o.y = acc[i][j][1] + bv4.y;
            o.z = acc[i][j][2] + bv4.z;
            o.w = acc[i][j][3] + bv4.w;
            *reinterpret_cast<float4*>(&outB[(size_t)mrow * H + c0 + ncol]) = o;
        }
    }
}

extern "C" void kernel_launch(void* const* d_in, const int* in_sizes, int n_in,
                              void* d_out, int out_size, void* d_ws, size_t ws_size,
                              hipStream_t stream) {
    const float* hs = (const float*)d_in[0];
    const float* wq = (const float*)d_in[1];
    const float* bq = (const float*)d_in[2];
    const float* wk = (const float*)d_in[3];
    const float* bk = (const float*)d_in[4];
    const float* wv = (const float*)d_in[5];
    const float* bv = (const float*)d_in[6];

    unsigned short* A_pk = (unsigned short*)d_ws;                 // 50,331,648 B
    unsigned short* W_pk = A_pk + (size_t)A_TILES * 8192;         //  3,538,944 B
    float* biasb         = (float*)(W_pk + (size_t)W_TILES * 8192);

    hipLaunchKernelGGL(convert_pack, dim3(A_TILES + W_TILES), dim3(256), 0, stream,
                       hs, wq, wk, wv, bq, bk, bv, A_pk, W_pk, biasb);

    hipLaunchKernelGGL(qkv_gemm, dim3(NBLK), dim3(256), 0, stream,
                       A_pk, W_pk, biasb, (float*)d_out);
}

// Round 9
// 230.046 us; speedup vs baseline: 1.1405x; 1.1405x over previous
//
#include <hip/hip_runtime.h>
#include <hip/hip_bf16.h>

// C[32768,2304] = A[32768,768] * W^T + b ; outputs q,k,v [32768,768] fp32 each.
#define M_TOT 32768
#define K_TOT 768
#define N_TOT 2304
#define H     768
#define BM 128
#define BN 128
#define BK 64
#define NBN 18                   // N_TOT/BN
#define NBM 256                  // M_TOT/BM
#define NBLK (NBM*NBN)           // 4608
#define NKT  (K_TOT/BK)          // 12
#define TILE_ELEMS 8192          // 128 rows x 64 k
#define OUT_PER 25165824         // M_TOT*H

typedef __attribute__((ext_vector_type(8))) short bf16x8;
typedef __attribute__((ext_vector_type(8))) unsigned short u16x8;
typedef __attribute__((ext_vector_type(4))) float f32x4;

__device__ __forceinline__ void gld_lds16(const void* g, void* l) {
    __builtin_amdgcn_global_load_lds(
        (const __attribute__((address_space(1))) unsigned int*)g,
        (__attribute__((address_space(3))) unsigned int*)l,
        16, 0, 0);
}

__device__ __forceinline__ unsigned short f2bf_rne(float f) {
    unsigned u = __builtin_bit_cast(unsigned, f);
    unsigned r = (u + 0x7FFFu + ((u >> 16) & 1u)) >> 16;
    return (unsigned short)r;
}

// ---------------------------------------------------------------------------
// Pass 1 (R3-proven, ~25us): fp32 -> bf16 convert + pack into tiled layout
// pk[gran][kt][kb8][row128][8]; granule = 128 rows x 768 k.
// ---------------------------------------------------------------------------
#define A_TILES 3072             // 256 m-granules x 12 k-tiles
#define W_TILES 216              // 18 row-granules x 12 k-tiles
#define LDSW 68

__global__ void convert_pack(const float* __restrict__ A,
                             const float* __restrict__ wq, const float* __restrict__ wk,
                             const float* __restrict__ wv,
                             const float* __restrict__ bq, const float* __restrict__ bk,
                             const float* __restrict__ bv,
                             unsigned short* __restrict__ A_pk,
                             unsigned short* __restrict__ W_pk,
                             float* __restrict__ biasb) {
    __shared__ float lds_f[128 * LDSW];

    const int tid = threadIdx.x;
    const int t   = blockIdx.x;

    int gt = t * 256 + tid;
    if (gt < 2304) {
        biasb[gt] = (gt < 768) ? bq[gt] : (gt < 1536) ? bk[gt - 768] : bv[gt - 1536];
    }

    const float* src;
    unsigned short* dst;
    if (t < A_TILES) {
        const int mt = t / 12, kt = t - mt * 12;
        src = A + (size_t)mt * 128 * K_TOT + kt * 64;
        dst = A_pk + (size_t)t * TILE_ELEMS;
    } else {
        const int t2 = t - A_TILES;
        const int nt = t2 / 12, kt = t2 - nt * 12;
        const int which = nt / 6;
        const int row0  = (nt - which * 6) * 128;
        const float* w = (which == 0) ? wq : (which == 1) ? wk : wv;
        src = w + (size_t)row0 * K_TOT + kt * 64;
        dst = W_pk + (size_t)t2 * TILE_ELEMS;
    }

    #pragma unroll
    for (int j = 0; j < 8; ++j) {
        int f = j * 256 + tid;
        int row = f >> 4, c4 = f & 15;
        float4 v = *reinterpret_cast<const float4*>(src + (size_t)row * K_TOT + c4 * 4);
        *reinterpret_cast<float4*>(&lds_f[row * LDSW + c4 * 4]) = v;
    }
    __syncthreads();

    #pragma unroll
    for (int j = 0; j < 4; ++j) {
        int c = j * 256 + tid;
        int kb = c >> 7, row = c & 127;
        const float* p = &lds_f[row * LDSW + kb * 8];
        u16x8 o;
        #pragma unroll
        for (int e = 0; e < 8; ++e) o[e] = f2bf_rne(p[e]);
        *reinterpret_cast<u16x8*>(dst + (size_t)c * 8) = o;
    }
}

// ---------------------------------------------------------------------------
// Pass 2: R3-proven 128x128 BK=64 compiler-scheduled GEMM, plus:
//   (a) stripe-locality grid: xcd = bid&7, each XCD runs contiguous groups of
//       all 18 n-blocks of one m-stripe -> A-stripe shared in L2, W (3.5 MB)
//       L2-resident per XCD, staged loads become L2/L3 hits (drain ~200-450
//       cyc instead of ~900) -- attacks the measured latency-bound regime.
//   (b) __launch_bounds__(256,5): 32 KiB LDS -> 5 blocks/CU.
//   (c) non-temporal C stores (via ext-vector f32x4): write-once output
//       doesn't evict A/W from L2/L3.
// ---------------------------------------------------------------------------
__global__ __launch_bounds__(256, 5) void qkv_gemm(
        const unsigned short* __restrict__ A_pk,
        const unsigned short* __restrict__ W_pk,
        const float* __restrict__ bias,
        float* __restrict__ out) {

    __shared__ __align__(16) unsigned short sA[TILE_ELEMS];
    __shared__ __align__(16) unsigned short sB[TILE_ELEMS];

    const int tid  = threadIdx.x;
    const int lane = tid & 63;
    const int wid  = tid >> 6;
    const int wr   = wid >> 1;       // 0..1 : rows wr*64..+63
    const int wc   = wid & 1;        // 0..1 : cols wc*64..+63

    // stripe-locality mapping (bijective): XCD c gets stripes {c, 8+c, 16+c, 24+c},
    // each as 18 consecutive-in-dispatch blocks covering all n-tiles.
    const int bid0   = (int)blockIdx.x;
    const int xcd    = bid0 & 7;
    const int idx    = bid0 >> 3;        // 0..575
    const int stripe = idx / NBN;        // 0..31
    const int bn     = idx - stripe * NBN;
    const int bm     = stripe * 8 + xcd; // 0..255
    const int m0 = bm * BM;
    const int n0 = bn * BN;

    f32x4 acc[4][4];
    #pragma unroll
    for (int i = 0; i < 4; i++)
        #pragma unroll
        for (int j = 0; j < 4; j++)
            acc[i][j] = (f32x4){0.f, 0.f, 0.f, 0.f};

    const unsigned short* aT = A_pk + (size_t)bm * NKT * TILE_ELEMS;
    const unsigned short* bT = W_pk + (size_t)bn * NKT * TILE_ELEMS;

    // fragment read offsets (bytes) in packed LDS [kb][row][8]
    const int aBase = (((lane >> 4) << 10) + (wr * 64 + (lane & 15)) * 8) * 2;
    const int bBase = (((lane >> 4) << 10) + (wc * 64 + (lane & 15)) * 8) * 2;

    for (int kt = 0; kt < NKT; ++kt) {
        if (kt) __syncthreads();
        const unsigned short* aS = aT + kt * TILE_ELEMS;
        const unsigned short* bS = bT + kt * TILE_ELEMS;
        #pragma unroll
        for (int i = 0; i < 4; i++) {
            const int c = i * 256 + tid;
            gld_lds16(aS + c * 8, &sA[c * 8]);
            gld_lds16(bS + c * 8, &sB[c * 8]);
        }
        __syncthreads();

        #pragma unroll
        for (int kk = 0; kk < 2; kk++) {
            bf16x8 af[4], bf[4];
            #pragma unroll
            for (int i = 0; i < 4; i++)
                af[i] = *reinterpret_cast<const bf16x8*>(
                    (const char*)sA + aBase + i * 256 + kk * 8192);
            #pragma unroll
            for (int j = 0; j < 4; j++)
                bf[j] = *reinterpret_cast<const bf16x8*>(
                    (const char*)sB + bBase + j * 256 + kk * 8192);
            #pragma unroll
            for (int i = 0; i < 4; i++)
                #pragma unroll
                for (int j = 0; j < 4; j++)
                    // swapped operands: lane's 4 acc regs = 4 consecutive n
                    acc[i][j] = __builtin_amdgcn_mfma_f32_16x16x32_bf16(
                        bf[j], af[i], acc[i][j], 0, 0, 0);
        }
    }

    // epilogue: lane holds m = frag_m0 + (lane&15), n = frag_n0 + (lane>>4)*4 + reg
    const int which = n0 / H;
    const int c0    = n0 - which * H;
    float* outB = out + (size_t)which * OUT_PER;

    #pragma unroll
    for (int j = 0; j < 4; ++j) {
        const int ncol = wc * 64 + j * 16 + ((lane >> 4) << 2);
        const float4 bv4 = *reinterpret_cast<const float4*>(&bias[n0 + ncol]);
        #pragma unroll
        for (int i = 0; i < 4; ++i) {
            const int mrow = m0 + wr * 64 + i * 16 + (lane & 15);
            f32x4 o;
            o[0] = acc[i][j][0] + bv4.x;
            o[1] = acc[i][j][1] + bv4.y;
            o[2] = acc[i][j][2] + bv4.z;
            o[3] = acc[i][j][3] + bv4.w;
            __builtin_nontemporal_store(o,
                reinterpret_cast<f32x4*>(&outB[(size_t)mrow * H + c0 + ncol]));
        }
    }
}

extern "C" void kernel_launch(void* const* d_in, const int* in_sizes, int n_in,
                              void* d_out, int out_size, void* d_ws, size_t ws_size,
                              hipStream_t stream) {
    const float* hs = (const float*)d_in[0];
    const float* wq = (const float*)d_in[1];
    const float* bq = (const float*)d_in[2];
    const float* wk = (const float*)d_in[3];
    const float* bk = (const float*)d_in[4];
    const float* wv = (const float*)d_in[5];
    const float* bv = (const float*)d_in[6];

    unsigned short* A_pk = (unsigned short*)d_ws;                 // 50,331,648 B
    unsigned short* W_pk = A_pk + (size_t)A_TILES * TILE_ELEMS;   //  3,538,944 B
    float* biasb         = (float*)(W_pk + (size_t)W_TILES * TILE_ELEMS);

    hipLaunchKernelGGL(convert_pack, dim3(A_TILES + W_TILES), dim3(256), 0, stream,
                       hs, wq, wk, wv, bq, bk, bv, A_pk, W_pk, biasb);

    hipLaunchKernelGGL(qkv_gemm, dim3(NBLK), dim3(256), 0, stream,
                       A_pk, W_pk, biasb, (float*)d_out);
}

// Round 12
// 157.808 us; speedup vs baseline: 1.6625x; 1.4578x over previous
//
#include <hip/hip_runtime.h>
#include <hip/hip_bf16.h>

// C[32768,2304] = A[32768,768] * W^T + b ; outputs q,k,v [32768,768] fp32 each.
#define M_TOT 32768
#define K_TOT 768
#define N_TOT 2304
#define H     768
#define BM 128
#define BN 128
#define BK 64
#define NBN 18                   // N_TOT/BN
#define NBM 256                  // M_TOT/BM
#define NBLK (NBM*NBN)           // 4608, %8==0 -> XCD swizzle bijective
#define NKT  (K_TOT/BK)          // 12
#define TILE_ELEMS 8192          // 128 rows x 64 k
#define OUT_PER 25165824         // M_TOT*H

typedef __attribute__((ext_vector_type(8))) short bf16x8;
typedef __attribute__((ext_vector_type(8))) unsigned short u16x8;
typedef __attribute__((ext_vector_type(4))) float f32x4;

__device__ __forceinline__ void gld_lds16(const void* g, void* l) {
    __builtin_amdgcn_global_load_lds(
        (const __attribute__((address_space(1))) unsigned int*)g,
        (__attribute__((address_space(3))) unsigned int*)l,
        16, 0, 0);
}

__device__ __forceinline__ unsigned short f2bf_rne(float f) {
    unsigned u = __builtin_bit_cast(unsigned, f);
    unsigned r = (u + 0x7FFFu + ((u >> 16) & 1u)) >> 16;
    return (unsigned short)r;
}

// ---------------------------------------------------------------------------
// Pass 1 (R3-proven, ~25us): fp32 -> bf16 convert + pack into tiled layout
// pk[gran][kt][kb8][row128][8]; granule = 128 rows x 768 k.
// Normal (caching) stores on purpose: A_pk/W_pk should LAND in L2/L3 for the
// GEMM to hit.
// ---------------------------------------------------------------------------
#define A_TILES 3072             // 256 m-granules x 12 k-tiles
#define W_TILES 216              // 18 row-granules x 12 k-tiles
#define LDSW 68

__global__ void convert_pack(const float* __restrict__ A,
                             const float* __restrict__ wq, const float* __restrict__ wk,
                             const float* __restrict__ wv,
                             const float* __restrict__ bq, const float* __restrict__ bk,
                             const float* __restrict__ bv,
                             unsigned short* __restrict__ A_pk,
                             unsigned short* __restrict__ W_pk,
                             float* __restrict__ biasb) {
    __shared__ float lds_f[128 * LDSW];

    const int tid = threadIdx.x;
    const int t   = blockIdx.x;

    int gt = t * 256 + tid;
    if (gt < 2304) {
        biasb[gt] = (gt < 768) ? bq[gt] : (gt < 1536) ? bk[gt - 768] : bv[gt - 1536];
    }

    const float* src;
    unsigned short* dst;
    if (t < A_TILES) {
        const int mt = t / 12, kt = t - mt * 12;
        src = A + (size_t)mt * 128 * K_TOT + kt * 64;
        dst = A_pk + (size_t)t * TILE_ELEMS;
    } else {
        const int t2 = t - A_TILES;
        const int nt = t2 / 12, kt = t2 - nt * 12;
        const int which = nt / 6;
        const int row0  = (nt - which * 6) * 128;
        const float* w = (which == 0) ? wq : (which == 1) ? wk : wv;
        src = w + (size_t)row0 * K_TOT + kt * 64;
        dst = W_pk + (size_t)t2 * TILE_ELEMS;
    }

    #pragma unroll
    for (int j = 0; j < 8; ++j) {
        int f = j * 256 + tid;
        int row = f >> 4, c4 = f & 15;
        float4 v = *reinterpret_cast<const float4*>(src + (size_t)row * K_TOT + c4 * 4);
        *reinterpret_cast<float4*>(&lds_f[row * LDSW + c4 * 4]) = v;
    }
    __syncthreads();

    #pragma unroll
    for (int j = 0; j < 4; ++j) {
        int c = j * 256 + tid;
        int kb = c >> 7, row = c & 127;
        const float* p = &lds_f[row * LDSW + kb * 8];
        u16x8 o;
        #pragma unroll
        for (int e = 0; e < 8; ++e) o[e] = f2bf_rne(p[e]);
        *reinterpret_cast<u16x8*>(dst + (size_t)c * 8) = o;
    }
}

// ---------------------------------------------------------------------------
// Pass 2: R3-proven 128x128 BK=64 compiler-scheduled GEMM. New in R10:
//   C-epilogue bounces through LDS (overlaid on sA/sB) and issues
//   FULLY-COALESCED non-temporal stores: 512B contiguous per 32 lanes,
//   128B-aligned -> no L2-line RMW amplification (R9's 596MB bug), and C
//   bypasses L2/L3 so A_pk/W_pk (54MB) stay L3-resident -> staging loads
//   become L3 hits instead of ~900cyc HBM misses (the measured latency wall).
// ---------------------------------------------------------------------------
__global__ __launch_bounds__(256, 4) void qkv_gemm(
        const unsigned short* __restrict__ A_pk,
        const unsigned short* __restrict__ W_pk,
        const float* __restrict__ bias,
        float* __restrict__ out) {

    // overlay: main loop uses 32KB (sA 16KB + sB 16KB); epilogue reuses the
    // same memory as a 64x132 f32 staging tile (33792 B).
    __shared__ __align__(16) unsigned char smem[64 * 132 * 4];
    unsigned short* sA = (unsigned short*)smem;
    unsigned short* sB = (unsigned short*)(smem + 16384);
    float* sC = (float*)smem;

    const int tid  = threadIdx.x;
    const int lane = tid & 63;
    const int wid  = tid >> 6;
    const int wr   = wid >> 1;       // 0..1 : rows wr*64..+63
    const int wc   = wid & 1;        // 0..1 : cols wc*64..+63

    int bid = (int)blockIdx.x;
    bid = (bid & 7) * (NBLK / 8) + (bid >> 3);     // XCD-aware (bijective)
    const int bm = bid / NBN;
    const int bn = bid - bm * NBN;
    const int m0 = bm * BM;
    const int n0 = bn * BN;

    f32x4 acc[4][4];
    #pragma unroll
    for (int i = 0; i < 4; i++)
        #pragma unroll
        for (int j = 0; j < 4; j++)
            acc[i][j] = (f32x4){0.f, 0.f, 0.f, 0.f};

    const unsigned short* aT = A_pk + (size_t)bm * NKT * TILE_ELEMS;
    const unsigned short* bT = W_pk + (size_t)bn * NKT * TILE_ELEMS;

    // fragment read offsets (bytes) in packed LDS [kb][row][8]
    const int aBase = (((lane >> 4) << 10) + (wr * 64 + (lane & 15)) * 8) * 2;
    const int bBase = (((lane >> 4) << 10) + (wc * 64 + (lane & 15)) * 8) * 2;

    for (int kt = 0; kt < NKT; ++kt) {
        if (kt) __syncthreads();
        const unsigned short* aS = aT + kt * TILE_ELEMS;
        const unsigned short* bS = bT + kt * TILE_ELEMS;
        #pragma unroll
        for (int i = 0; i < 4; i++) {
            const int c = i * 256 + tid;
            gld_lds16(aS + c * 8, &sA[c * 8]);
            gld_lds16(bS + c * 8, &sB[c * 8]);
        }
        __syncthreads();

        #pragma unroll
        for (int kk = 0; kk < 2; kk++) {
            bf16x8 af[4], bf[4];
            #pragma unroll
            for (int i = 0; i < 4; i++)
                af[i] = *reinterpret_cast<const bf16x8*>(
                    (const char*)sA + aBase + i * 256 + kk * 8192);
            #pragma unroll
            for (int j = 0; j < 4; j++)
                bf[j] = *reinterpret_cast<const bf16x8*>(
                    (const char*)sB + bBase + j * 256 + kk * 8192);
            #pragma unroll
            for (int i = 0; i < 4; i++)
                #pragma unroll
                for (int j = 0; j < 4; j++)
                    // swapped operands: lane's 4 acc regs = 4 consecutive n
                    acc[i][j] = __builtin_amdgcn_mfma_f32_16x16x32_bf16(
                        bf[j], af[i], acc[i][j], 0, 0, 0);
        }
    }

    // ---- epilogue: LDS transpose-stage (2 halves of 2 i-stripes each), then
    // coalesced 512B-per-32-lane nt stores (128B-aligned, no RMW).
    const int which = n0 / H;
    const int c0    = n0 - which * H;
    float* outB = out + (size_t)which * OUT_PER + (size_t)m0 * H + c0;

    #pragma unroll
    for (int half = 0; half < 2; ++half) {
        __syncthreads();   // LDS free (main loop reads / prev half stores done)
        #pragma unroll
        for (int il = 0; il < 2; ++il) {
            const int i    = half * 2 + il;
            const int wrow = wr * 32 + il * 16 + (lane & 15);
            #pragma unroll
            for (int j = 0; j < 4; ++j) {
                const int col = wc * 64 + j * 16 + ((lane >> 4) << 2);
                const float4 bv4 = *reinterpret_cast<const float4*>(&bias[n0 + col]);
                f32x4 o;
                o[0] = acc[i][j][0] + bv4.x;
                o[1] = acc[i][j][1] + bv4.y;
                o[2] = acc[i][j][2] + bv4.z;
                o[3] = acc[i][j][3] + bv4.w;
                *reinterpret_cast<f32x4*>(&sC[wrow * 132 + col]) = o;
            }
        }
        __syncthreads();
        // read back + nt store: flat = row*32 + chunk; 32 lanes cover one full
        // 512B row segment -> perfectly coalesced, 128B-aligned.
        #pragma unroll
        for (int v = 0; v < 8; ++v) {
            const int flat  = v * 256 + tid;
            const int row   = flat >> 5;       // 0..63 (LDS row)
            const int chunk = flat & 31;       // 16B chunk in row
            f32x4 o = *reinterpret_cast<const f32x4*>(&sC[row * 132 + chunk * 4]);
            // LDS row -> global row: wr=row>>5, low5=row&31 (il*16+rr)
            const int grow = ((row >> 5) << 6) + half * 32 + (row & 31);
            __builtin_nontemporal_store(o,
                reinterpret_cast<f32x4*>(&outB[(size_t)grow * H + chunk * 4]));
        }
    }
}

extern "C" void kernel_launch(void* const* d_in, const int* in_sizes, int n_in,
                              void* d_out, int out_size, void* d_ws, size_t ws_size,
                              hipStream_t stream) {
    const float* hs = (const float*)d_in[0];
    const float* wq = (const float*)d_in[1];
    const float* bq = (const float*)d_in[2];
    const float* wk = (const float*)d_in[3];
    const float* bk = (const float*)d_in[4];
    const float* wv = (const float*)d_in[5];
    const float* bv = (const float*)d_in[6];

    unsigned short* A_pk = (unsigned short*)d_ws;                 // 50,331,648 B
    unsigned short* W_pk = A_pk + (size_t)A_TILES * TILE_ELEMS;   //  3,538,944 B
    float* biasb         = (float*)(W_pk + (size_t)W_TILES * TILE_ELEMS);

    hipLaunchKernelGGL(convert_pack, dim3(A_TILES + W_TILES), dim3(256), 0, stream,
                       hs, wq, wk, wv, bq, bk, bv, A_pk, W_pk, biasb);

    hipLaunchKernelGGL(qkv_gemm, dim3(NBLK), dim3(256), 0, stream,
                       A_pk, W_pk, biasb, (float*)d_out);
}